// Round 5
// baseline (252.460 us; speedup 1.0000x reference)
//
#include <hip/hip_runtime.h>
#include <hip/hip_bf16.h>

// Problem constants (from reference)
#define P_TOTAL 16384      // H*W pixels
#define KN      16         // kernels per pixel
#define CK      144        // in_channel * kernel_size
#define BATCH   8
#define IMG     262144     // C*H*W
#define PSTRIDE 12         // LDS row stride in floats (48B, 16B-aligned for b128)

// ---------------- transpose+quantize: x[b][id] (f32) -> xt[id][b] (bf16) ----------------
// xt = 4.19 MB, read-only, ~9x average reuse per line in the gather. Everything
// else in the pipeline is single-use and loaded non-temporally so xt is the
// ONLY tenant of the per-XCD L2s.
__global__ __launch_bounds__(256) void transpose_x_bf16(
    const float* __restrict__ x, float4* __restrict__ xt)
{
    const int i = blockIdx.x * 256 + threadIdx.x;   // id in [0, IMG)
    union { __hip_bfloat16 h[8]; float4 f4; } u;
#pragma unroll
    for (int b = 0; b < BATCH; ++b)
        u.h[b] = __float2bfloat16(__builtin_nontemporal_load(x + (size_t)b * IMG + i));
    xt[i] = u.f4;   // NORMAL store: leave xt resident in L2
}

// ---------------- main kernel ----------------
template <bool USE_XT>
__global__ __launch_bounds__(256) void abc2d_kernel(
    const void*  __restrict__ xsrc,   // USE_XT ? xt bf16 [IMG][8] : x f32 [8][IMG]
    const float* __restrict__ w,      // [P, KN, CK]
    const int*   __restrict__ hidx,   // [P, CK]
    float* __restrict__ out)          // [B, KN, P]
{
    __shared__ float patch[CK * PSTRIDE];   // patch[c][b], f32

    // XCD swizzle: consecutive p on the same XCD -> output lines merge in L2
    const int bid = blockIdx.x;
    const int p   = (bid & 7) * (P_TOTAL / 8) + (bid >> 3);
    const int t   = threadIdx.x;
    const int k   = t >> 4;
    const int cs  = t & 15;

    // ---- weight prefetch (non-temporal: 151 MB single-use stream must not
    // evict xt from L2). Issued before the gather so latencies overlap. ----
    const float* wp = w + (size_t)p * (KN * CK) + (size_t)k * CK;
    float wreg[9];
#pragma unroll
    for (int i = 0; i < 9; ++i)
        wreg[i] = __builtin_nontemporal_load(wp + cs + 16 * i);  // 16-lane 64B runs

    // ---------- gather phase ----------
    const int* hp = hidx + p * CK;
    if (USE_XT) {
        // one index per thread: 16B bf16x8 load (NORMAL: wants L2 hits)
        if (t < CK) {
            const int id = __builtin_nontemporal_load(hp + t);   // hidx single-use
            union { __hip_bfloat16 h[8]; float4 f4; } u;
            u.f4 = reinterpret_cast<const float4*>(xsrc)[id];
            float* pr = &patch[t * PSTRIDE];
            *reinterpret_cast<float4*>(pr) = make_float4(
                __bfloat162float(u.h[0]), __bfloat162float(u.h[1]),
                __bfloat162float(u.h[2]), __bfloat162float(u.h[3]));
            *reinterpret_cast<float4*>(pr + 4) = make_float4(
                __bfloat162float(u.h[4]), __bfloat162float(u.h[5]),
                __bfloat162float(u.h[6]), __bfloat162float(u.h[7]));
        }
    } else {
        const float* xf = reinterpret_cast<const float*>(xsrc);
        for (int j = t; j < CK * BATCH; j += 256) {
            const int c = j >> 3;
            const int b = j & 7;
            patch[c * PSTRIDE + b] = xf[(size_t)hp[c] + (size_t)b * IMG];
        }
    }
    __syncthreads();

    // ---------- compute phase ----------
    // c = cs + 16*i: LDS word-step 12/lane, gcd(12,32)=4 -> 2-way alias = free
    float acc[BATCH];
#pragma unroll
    for (int b = 0; b < BATCH; ++b) acc[b] = 0.f;

#pragma unroll
    for (int i = 0; i < 9; ++i) {
        const int c = cs + 16 * i;
        const float wv = wreg[i];
        const float* pr = &patch[c * PSTRIDE];
        const float4 p0 = *reinterpret_cast<const float4*>(pr);
        const float4 p1 = *reinterpret_cast<const float4*>(pr + 4);
        acc[0] += wv * p0.x;
        acc[1] += wv * p0.y;
        acc[2] += wv * p0.z;
        acc[3] += wv * p0.w;
        acc[4] += wv * p1.x;
        acc[5] += wv * p1.y;
        acc[6] += wv * p1.z;
        acc[7] += wv * p1.w;
    }

    // ---------- reduce across 16 cs lanes ----------
#pragma unroll
    for (int b = 0; b < BATCH; ++b) {
        float v = acc[b];
        v += __shfl_xor(v, 1);
        v += __shfl_xor(v, 2);
        v += __shfl_xor(v, 4);
        v += __shfl_xor(v, 8);
        acc[b] = v;
    }

    if (cs == 0) {
#pragma unroll
        for (int b = 0; b < BATCH; ++b)
            __builtin_nontemporal_store(acc[b],
                out + (size_t)b * (KN * P_TOTAL) + (size_t)k * P_TOTAL + p);  // write-once
    }
}

extern "C" void kernel_launch(void* const* d_in, const int* in_sizes, int n_in,
                              void* d_out, int out_size, void* d_ws, size_t ws_size,
                              hipStream_t stream) {
    const float* x    = (const float*)d_in[0];   // [8,16,128,128] f32
    const float* wts  = (const float*)d_in[1];   // [16384,16,144] f32
    const int*   hidx = (const int*)d_in[2];     // [16384,144] int32
    float* out = (float*)d_out;                  // [8,16,16384] f32

    const size_t xt_bytes = (size_t)IMG * BATCH * sizeof(__hip_bfloat16);  // 4.19 MB
    if (ws_size >= xt_bytes) {
        float4* xt = (float4*)d_ws;
        transpose_x_bf16<<<IMG / 256, 256, 0, stream>>>(x, xt);
        abc2d_kernel<true><<<P_TOTAL, 256, 0, stream>>>((const void*)xt, wts, hidx, out);
    } else {
        abc2d_kernel<false><<<P_TOTAL, 256, 0, stream>>>((const void*)x, wts, hidx, out);
    }
}

// Round 6
// 241.385 us; speedup vs baseline: 1.0459x; 1.0459x over previous
//
#include <hip/hip_runtime.h>
#include <hip/hip_bf16.h>

// Problem constants
#define P_TOTAL 16384      // H*W pixels
#define KN      16         // kernels per pixel
#define CK      144        // in_channel * kernel_size
#define BATCH   8
#define IMG     262144     // C*H*W
#define RWH     176        // patchT row stride in halfwords (88 words = 352B, 16B-aligned)

typedef __attribute__((ext_vector_type(8))) short bf16x8;   // 4 VGPRs: MFMA A/B frag
typedef __attribute__((ext_vector_type(4))) float f32x4;    // MFMA C/D frag

__device__ __forceinline__ short f2bf(float f) {
    __hip_bfloat16 h = __float2bfloat16(f);
    return *reinterpret_cast<short*>(&h);
}

// ---------------- transpose+quantize: x[b][id] (f32) -> xt[id][b] (bf16) ----------------
// One gather index = one 16B chunk (single line). Plain loads (NT regressed in R5).
__global__ __launch_bounds__(256) void transpose_x_bf16(
    const float* __restrict__ x, float4* __restrict__ xt)
{
    const int i = blockIdx.x * 256 + threadIdx.x;
    union { short h[8]; float4 f4; } u;
#pragma unroll
    for (int b = 0; b < BATCH; ++b)
        u.h[b] = f2bf(x[(size_t)b * IMG + i]);
    xt[i] = u.f4;
}

// ---------------- main kernel: one wave per pixel, MFMA compute ----------------
// D[b(16,8 real)][k(16)] = patchT[b][c] * W[k][c]^T,  5x mfma_f32_16x16x32_bf16 (K=160, zero-pad)
// No __syncthreads: each wave has a private LDS segment. No shuffle reduction.
__global__ __launch_bounds__(256) void abc2d_mfma(
    const float4* __restrict__ xt,    // bf16 [IMG][8]
    const float*  __restrict__ w,     // [P, KN, CK] f32
    const int*    __restrict__ hidx,  // [P, CK]
    float* __restrict__ out)          // [B, KN, P] f32
{
    __shared__ short patchT[4 * 8 * RWH];   // 4 waves x [8 b-rows][176 halfwords] = 11264 B

    const int t    = threadIdx.x;
    const int wv   = t >> 6;
    const int lane = t & 63;
    const int bid  = blockIdx.x;
    // XCD swizzle: XCD x owns p in [x*2048,(x+1)*2048); same-XCD blocks adjacent in p
    const int p = (bid & 7) * (P_TOTAL / 8) + (bid >> 3) * 4 + wv;

    short* pT = patchT + wv * 8 * RWH;      // this wave's segment

    // ---------- gather: 144 indices over 64 lanes (2.25 each) ----------
    const int* hp = hidx + p * CK;
    const int c0 = lane, c1 = lane + 64;
    const int id0 = hp[c0];
    const int id1 = hp[c1];
    int id2 = 0;
    if (lane < 16) id2 = hp[lane + 128];
    union { short h[8]; float4 f4; } u0, u1, u2;
    u0.f4 = xt[id0];
    u1.f4 = xt[id1];
    if (lane < 16) u2.f4 = xt[id2];
#pragma unroll
    for (int b = 0; b < BATCH; ++b) pT[b * RWH + c0] = u0.h[b];   // b16 scatter: 2 lanes/word = free
#pragma unroll
    for (int b = 0; b < BATCH; ++b) pT[b * RWH + c1] = u1.h[b];
    if (lane < 16) {
#pragma unroll
        for (int b = 0; b < BATCH; ++b) pT[b * RWH + lane + 128] = u2.h[b];
    }
    // zero-pad c=144..159 (K padded to 160): 8 rows x 8 words, one b32 write per lane
    reinterpret_cast<int*>(pT)[(lane >> 3) * 88 + 72 + (lane & 7)] = 0;

    // ---------- MFMA compute (wave-internal dep on own LDS; no barrier) ----------
    const int n    = lane & 15;          // output k; A-row selector
    const int q    = lane >> 4;          // K-quad
    const int arow = n & 7;              // lanes 8-15 broadcast rows 0-7 (dup rows discarded)
    const short* aptr = pT + arow * RWH;
    const float* wp   = w + (size_t)p * (KN * CK) + (size_t)n * CK;

    f32x4 acc = {0.f, 0.f, 0.f, 0.f};
#pragma unroll
    for (int s = 0; s < 5; ++s) {
        const int c = 32 * s + 8 * q;
        bf16x8 a = *reinterpret_cast<const bf16x8*>(aptr + c);   // 16B, 16B-aligned
        bf16x8 b = {0, 0, 0, 0, 0, 0, 0, 0};
        if (c < CK) {   // s=4,q>=2 -> zero frag (A side also zeroed)
            const float4 f0 = *reinterpret_cast<const float4*>(wp + c);
            const float4 f1 = *reinterpret_cast<const float4*>(wp + c + 4);
            b[0] = f2bf(f0.x); b[1] = f2bf(f0.y); b[2] = f2bf(f0.z); b[3] = f2bf(f0.w);
            b[4] = f2bf(f1.x); b[5] = f2bf(f1.y); b[6] = f2bf(f1.z); b[7] = f2bf(f1.w);
        }
        acc = __builtin_amdgcn_mfma_f32_16x16x32_bf16(a, b, acc, 0, 0, 0);
    }

    // ---------- store: C/D col=lane&15 (=k), row=q*4+i (=b); rows 8-15 are dups ----------
    if (lane < 32) {
#pragma unroll
        for (int i = 0; i < 4; ++i) {
            const int b = q * 4 + i;
            out[(size_t)b * (KN * P_TOTAL) + (size_t)n * P_TOTAL + p] = acc[i];
        }
    }
}

// ---------------- fallback (no workspace): R2-style scalar kernel ----------------
__global__ __launch_bounds__(256) void abc2d_fallback(
    const float* __restrict__ x, const float* __restrict__ w,
    const int* __restrict__ hidx, float* __restrict__ out)
{
    __shared__ float patch[CK * 12];
    const int bid = blockIdx.x;
    const int p   = (bid & 7) * (P_TOTAL / 8) + (bid >> 3);
    const int t   = threadIdx.x;
    const int* hp = hidx + p * CK;
    for (int j = t; j < CK * BATCH; j += 256) {
        const int c = j >> 3, b = j & 7;
        patch[c * 12 + b] = x[(size_t)hp[c] + (size_t)b * IMG];
    }
    __syncthreads();
    const int k = t >> 4, cs = t & 15;
    const float* wp = w + (size_t)p * (KN * CK) + (size_t)k * CK;
    float acc[BATCH];
#pragma unroll
    for (int b = 0; b < BATCH; ++b) acc[b] = 0.f;
#pragma unroll
    for (int i = 0; i < 9; ++i) {
        const int c = cs + 16 * i;
        const float wv = wp[c];
        const float* pr = &patch[c * 12];
#pragma unroll
        for (int b = 0; b < BATCH; ++b) acc[b] += wv * pr[b];
    }
#pragma unroll
    for (int b = 0; b < BATCH; ++b) {
        float v = acc[b];
        v += __shfl_xor(v, 1); v += __shfl_xor(v, 2);
        v += __shfl_xor(v, 4); v += __shfl_xor(v, 8);
        acc[b] = v;
    }
    if (cs == 0)
#pragma unroll
        for (int b = 0; b < BATCH; ++b)
            out[(size_t)b * (KN * P_TOTAL) + (size_t)k * P_TOTAL + p] = acc[b];
}

extern "C" void kernel_launch(void* const* d_in, const int* in_sizes, int n_in,
                              void* d_out, int out_size, void* d_ws, size_t ws_size,
                              hipStream_t stream) {
    const float* x    = (const float*)d_in[0];
    const float* wts  = (const float*)d_in[1];
    const int*   hidx = (const int*)d_in[2];
    float* out = (float*)d_out;

    const size_t xt_bytes = (size_t)IMG * BATCH * sizeof(short);   // 4.19 MB
    if (ws_size >= xt_bytes) {
        float4* xt = (float4*)d_ws;
        transpose_x_bf16<<<IMG / 256, 256, 0, stream>>>(x, xt);
        abc2d_mfma<<<P_TOTAL / 4, 256, 0, stream>>>(xt, wts, hidx, out);
    } else {
        abc2d_fallback<<<P_TOTAL, 256, 0, stream>>>(x, wts, hidx, out);
    }
}